// Round 4
// baseline (401.062 us; speedup 1.0000x reference)
//
#include <hip/hip_runtime.h>
#include <hip/hip_bf16.h>

typedef unsigned short u16;
typedef unsigned int u32;

#define DEVI __device__ __forceinline__

constexpr float SCALE = 0.0625f;   // 256^-0.5
constexpr float LN_EPS = 1e-5f;

DEVI float dot8f(const float* __restrict__ w, const float* __restrict__ x){
  float4 a = *(const float4*)w;
  float4 b = *(const float4*)(w + 4);
  return a.x*x[0]+a.y*x[1]+a.z*x[2]+a.w*x[3]+b.x*x[4]+b.y*x[5]+b.z*x[6]+b.w*x[7];
}

// ---------------- K0: slots = mu + exp(logsigma)*noise ----------------
__global__ void k_init_slots(const float* __restrict__ noise, const float* __restrict__ smu,
                             const float* __restrict__ slsig, float* __restrict__ slots){
  const int r = blockIdx.x, tid = threadIdx.x;
  const int s = r & 7;
  slots[r*256 + tid] = smu[s*256 + tid] + expf(slsig[s*256 + tid]) * noise[r*256 + tid];
}

// ---------------- K1: per (b,s): qg = SCALE*g_in*( (LN_s(slots)@Wq^T)@Wk[s] ), plus Gq,Bq
// Also zeroes uacc/Zacc for this iteration's k_main atomic accumulation.
__global__ __launch_bounds__(256) void k_qg(const float* __restrict__ slots,
    const float* __restrict__ Wq, const float* __restrict__ Wk,
    const float* __restrict__ g_s, const float* __restrict__ be_s,
    const float* __restrict__ g_in, const float* __restrict__ be_in,
    float* __restrict__ qg, float* __restrict__ gqbq,
    float* __restrict__ uacc, float* __restrict__ Zacc){
  __shared__ float partQ[256][33];
  __shared__ float partK[8][256];
  __shared__ float sn[256];
  __shared__ float qv[256];
  __shared__ float red[8];
  const int r = blockIdx.x, tid = threadIdx.x;
  const int s = r & 7;
  const int lane = tid & 63, wv = tid >> 6;
  uacc[r*256 + tid] = 0.f;            // zero accumulators for k_main
  if (tid == 0) Zacc[r] = 0.f;
  float x = slots[r*256 + tid];
  float v1 = x, v2 = x*x;
  #pragma unroll
  for (int o = 32; o; o >>= 1){ v1 += __shfl_xor(v1,o,64); v2 += __shfl_xor(v2,o,64); }
  if (lane == 0){ red[wv] = v1; red[4+wv] = v2; }
  __syncthreads();
  {
    float mu = (red[0]+red[1]+red[2]+red[3]) * (1.f/256.f);
    float var = (red[4]+red[5]+red[6]+red[7]) * (1.f/256.f) - mu*mu;
    float inv = rsqrtf(var + LN_EPS);
    sn[tid] = (x - mu)*inv*g_s[tid] + be_s[tid];
  }
  __syncthreads();
  const int c8 = tid & 31, ep = tid >> 5;
  { // q[e] = sum_d sn[d]*Wq[e,d]
    float xs8[8];
    #pragma unroll
    for (int j = 0; j < 8; ++j) xs8[j] = sn[c8*8 + j];
    const float* Wb = Wq + c8*8;
    #pragma unroll 4
    for (int ei = 0; ei < 32; ++ei){
      int e = ep*32 + ei;
      partQ[e][c8] = dot8f(Wb + (size_t)e*256, xs8);
    }
  }
  __syncthreads();
  {
    float acc = 0.f;
    #pragma unroll
    for (int p = 0; p < 32; ++p) acc += partQ[tid][p];
    qv[tid] = acc;
  }
  __syncthreads();
  { // qk[d] = sum_e qv[e]*Wk[s,e,d]  (outer-product accumulation, coalesced along d)
    float acc8[8];
    #pragma unroll
    for (int j = 0; j < 8; ++j) acc8[j] = 0.f;
    const float* Wb = Wk + ((size_t)s*256)*256 + c8*8;
    #pragma unroll 4
    for (int ei = 0; ei < 32; ++ei){
      int e = ep*32 + ei;
      const float* wp = Wb + (size_t)e*256;
      float4 wa = *(const float4*)wp;
      float4 wb = *(const float4*)(wp + 4);
      float qe = qv[e];
      acc8[0] += qe*wa.x; acc8[1] += qe*wa.y; acc8[2] += qe*wa.z; acc8[3] += qe*wa.w;
      acc8[4] += qe*wb.x; acc8[5] += qe*wb.y; acc8[6] += qe*wb.z; acc8[7] += qe*wb.w;
    }
    float* pk = &partK[ep][c8*8];
    #pragma unroll
    for (int j = 0; j < 8; ++j) pk[j] = acc8[j];
  }
  __syncthreads();
  {
    float qk = 0.f;
    #pragma unroll
    for (int p = 0; p < 8; ++p) qk += partK[p][tid];
    float qgv = qk * g_in[tid] * SCALE;
    float bqv = qk * be_in[tid] * SCALE;
    qg[r*256 + tid] = qgv;
    float vq = qgv, vb = bqv;
    #pragma unroll
    for (int o = 32; o; o >>= 1){ vq += __shfl_xor(vq,o,64); vb += __shfl_xor(vb,o,64); }
    if (lane == 0){ red[wv] = vq; red[4+wv] = vb; }
  }
  __syncthreads();
  if (tid == 0) gqbq[r*2+0] = red[0]+red[1]+red[2]+red[3];
  if (tid == 1) gqbq[r*2+1] = red[4]+red[5]+red[6]+red[7];
}

// ---------------- K2: fused LN + dots + softmax(slots) + weighted-emb accumulation ----------------
// one block = 32-token tile of one batch. Atomically accumulates u and Z into uacc/Zacc.
__global__ __launch_bounds__(256) void k_main(const float* __restrict__ emb,
    const float* __restrict__ qg, const float* __restrict__ gqbq,
    const float* __restrict__ g_in, const float* __restrict__ be_in,
    float* __restrict__ uacc, float* __restrict__ Zacc,
    float* __restrict__ out_attn, int write_attn){
  __shared__ __align__(16) float Xs[32*260];   // fp32 tile, row stride 260 (16B-aligned rows)
  __shared__ float qgL[8*256];
  __shared__ float aL[8*32];
  __shared__ float avL[8*32];
  __shared__ float muL[32], invL[32];
  __shared__ float Wred[2][8][4];
  __shared__ float Zs[8], A2s[8], GqL[8], BqL[8];

  const int tid = threadIdx.x;
  const int lane = tid & 63;
  const int wv = tid >> 6;
  const int blk = blockIdx.x;
  const int b = blk >> 7;
  const int tile = blk & 127;
  const int n0 = tile * 32;

  { // this batch's 8 query vectors (g_in*SCALE-folded)
    const float4* src = (const float4*)(qg + (size_t)b * 2048);
    float4* dst = (float4*)qgL;
    dst[tid] = src[tid];
    dst[tid + 256] = src[tid + 256];
  }
  if (tid < 8){
    GqL[tid] = gqbq[(b*8 + tid)*2 + 0];
    BqL[tid] = gqbq[(b*8 + tid)*2 + 1];
  }
  { // stage 32x256 fp32 tile: coalesced 16B loads
    const float4* src = (const float4*)(emb + ((size_t)b*4096 + n0) * 256);
    #pragma unroll
    for (int k = 0; k < 8; ++k){
      int v = tid + 256*k;
      float4 u = src[v];
      int t = v >> 6;
      int c0 = (v & 63) * 4;
      *(float4*)(&Xs[t*260 + c0]) = u;
    }
  }
  __syncthreads();

  const int t = tid >> 3;   // token 0..31 (8 lanes per token)
  const int qq = tid & 7;   // 32-col chunk
  { // per-token LN stats
    const float4* xp = (const float4*)(&Xs[t*260 + qq*32]);
    float s1 = 0.f, s2 = 0.f;
    #pragma unroll
    for (int j = 0; j < 8; ++j){
      float4 u = xp[j];
      s1 += (u.x+u.y)+(u.z+u.w);
      s2 += u.x*u.x+u.y*u.y+u.z*u.z+u.w*u.w;
    }
    s1 += __shfl_xor(s1, 1, 64); s2 += __shfl_xor(s2, 1, 64);
    s1 += __shfl_xor(s1, 2, 64); s2 += __shfl_xor(s2, 2, 64);
    s1 += __shfl_xor(s1, 4, 64); s2 += __shfl_xor(s2, 4, 64);
    if (qq == 0){
      float mu = s1 * (1.f/256.f);
      float var = s2 * (1.f/256.f) - mu*mu;
      muL[t] = mu;
      invL[t] = rsqrtf(var + LN_EPS);
    }
  }
  __syncthreads();
  { // dots on raw x (LN folded via mu/inv/Gq/Bq), softmax over slots
    float acc[8];
    #pragma unroll
    for (int s = 0; s < 8; ++s) acc[s] = 0.f;
    const float4* xp = (const float4*)(&Xs[t*260 + qq*32]);
    #pragma unroll 2
    for (int j = 0; j < 8; ++j){
      float4 u = xp[j];
      const float* qb = &qgL[qq*32 + j*4];
      #pragma unroll
      for (int s = 0; s < 8; ++s){
        float4 q0 = *(const float4*)(qb + s*256);
        acc[s] += u.x*q0.x + u.y*q0.y + u.z*q0.z + u.w*q0.w;
      }
    }
    #pragma unroll
    for (int s = 0; s < 8; ++s){
      acc[s] += __shfl_xor(acc[s], 1, 64);
      acc[s] += __shfl_xor(acc[s], 2, 64);
      acc[s] += __shfl_xor(acc[s], 4, 64);
    }
    float mu = muL[t], inv = invL[t];
    float dv[8], mx = -1e30f;
    #pragma unroll
    for (int s = 0; s < 8; ++s){
      dv[s] = inv * (acc[s] - mu * GqL[s]) + BqL[s];
      mx = fmaxf(mx, dv[s]);
    }
    float den = 0.f;
    #pragma unroll
    for (int s = 0; s < 8; ++s){ dv[s] = expf(dv[s] - mx); den += dv[s]; }
    float rden = 1.f / den;
    #pragma unroll
    for (int s = 0; s < 8; ++s){
      float at = dv[s] * rden;       // attn (softmax over slots)
      float av = at * inv;           // attn * inv for LN-folded accumulation
      if (qq == 0){ avL[s*32 + t] = at; aL[s*32 + t] = av; }
      float z1 = at, z2 = av * mu;
      #pragma unroll
      for (int o = 32; o; o >>= 1){ z1 += __shfl_xor(z1, o, 64); z2 += __shfl_xor(z2, o, 64); }
      if (lane == 0){ Wred[0][s][wv] = z1 * 0.125f; Wred[1][s][wv] = z2 * 0.125f; }
    }
  }
  __syncthreads();
  if (tid < 8){
    Zs[tid]  = Wred[0][tid][0]+Wred[0][tid][1]+Wred[0][tid][2]+Wred[0][tid][3];
    A2s[tid] = Wred[1][tid][0]+Wred[1][tid][1]+Wred[1][tid][2]+Wred[1][tid][3];
  }
  if (write_attn){
    int s = tid >> 5, tk = tid & 31;
    out_attn[((size_t)(b*8 + s))*4096 + n0 + tk] = avL[s*32 + tk];
  }
  __syncthreads();
  { // block-partial u: u_part[s][c] = g_in[c]*(sum_t a[s][t]*x[t][c] - A2[s]) + be_in[c]*Z[s]
    const int c = tid;
    float S1[8];
    #pragma unroll
    for (int s = 0; s < 8; ++s) S1[s] = 0.f;
    #pragma unroll 2
    for (int t4 = 0; t4 < 8; ++t4){
      float x0 = Xs[(t4*4+0)*260 + c];
      float x1 = Xs[(t4*4+1)*260 + c];
      float x2 = Xs[(t4*4+2)*260 + c];
      float x3 = Xs[(t4*4+3)*260 + c];
      #pragma unroll
      for (int s = 0; s < 8; ++s){
        float4 a4 = *(const float4*)(&aL[s*32 + t4*4]);
        S1[s] += x0*a4.x + x1*a4.y + x2*a4.z + x3*a4.w;
      }
    }
    float gc = g_in[c];
    float bc = be_in[c];
    float* dst = uacc + ((size_t)b*8)*256 + c;
    #pragma unroll
    for (int s = 0; s < 8; ++s){
      atomicAdd(&dst[s*256], gc * (S1[s] - A2s[s]) + bc * Zs[s]);
    }
    if (tid < 8) atomicAdd(&Zacc[b*8 + tid], Zs[tid]);
  }
}

// ---------------- K3a: normalize by Z, apply Wv ----------------
__global__ __launch_bounds__(256) void k_updates(const float* __restrict__ uacc, const float* __restrict__ Zacc,
    const float* __restrict__ Wv, float* __restrict__ upd){
  __shared__ float part[256][33];
  __shared__ float uL[256];
  const int r = blockIdx.x, tid = threadIdx.x;
  const int s = r & 7;
  uL[tid] = uacc[r*256 + tid];
  __syncthreads();
  const float rz = 1.f / Zacc[r];
  const int c8 = tid & 31, dp = tid >> 5;
  float xs8[8];
  #pragma unroll
  for (int j = 0; j < 8; ++j) xs8[j] = uL[c8*8 + j];
  const float* Wb = Wv + ((size_t)s*256)*256 + c8*8;
  #pragma unroll 4
  for (int di = 0; di < 32; ++di){
    int d = dp*32 + di;
    part[d][c8] = dot8f(Wb + (size_t)d*256, xs8);
  }
  __syncthreads();
  float acc = 0.f;
  #pragma unroll
  for (int p = 0; p < 32; ++p) acc += part[tid][p];
  upd[r*256 + tid] = acc * rz;
}

// ---------------- K3b: the 6 GRU GEMVs, coalesced ----------------
__global__ __launch_bounds__(256) void k_gruGemv(const float* __restrict__ upd, const float* __restrict__ slots,
    const float* __restrict__ W_ih, const float* __restrict__ W_hh,
    const float* __restrict__ b_ih, const float* __restrict__ b_hh,
    float* __restrict__ gigh){
  __shared__ float xL[256];
  __shared__ float part[256][33];
  const int which = blockIdx.x;   // 0..5
  const int r = blockIdx.y;       // 0..127
  const int tid = threadIdx.x;
  const int g = (which < 3) ? which : which - 3;
  const float* xsrc = (which < 3) ? (upd + r*256) : (slots + r*256);
  const float* W = (which < 3) ? W_ih : W_hh;
  const float* bias = (which < 3) ? b_ih : b_hh;
  xL[tid] = xsrc[tid];
  __syncthreads();
  const int c8 = tid & 31, dp = tid >> 5;
  float xs8[8];
  #pragma unroll
  for (int j = 0; j < 8; ++j) xs8[j] = xL[c8*8 + j];
  const float* Wb = W + ((size_t)g*256)*256 + c8*8;
  #pragma unroll 4
  for (int di = 0; di < 32; ++di){
    int d = dp*32 + di;
    part[d][c8] = dot8f(Wb + (size_t)d*256, xs8);
  }
  __syncthreads();
  float acc = 0.f;
  #pragma unroll
  for (int p = 0; p < 32; ++p) acc += part[tid][p];
  gigh[((size_t)r*6 + which)*256 + tid] = acc + bias[g*256 + tid];
}

// ---------------- K3c: GRU gates + LN + MLP + residual ----------------
__global__ __launch_bounds__(256) void k_mlp(const float* __restrict__ gigh, float* __restrict__ slots,
    const float* __restrict__ W1, const float* __restrict__ b1,
    const float* __restrict__ W2, const float* __restrict__ b2,
    const float* __restrict__ g_ff, const float* __restrict__ be_ff,
    float* __restrict__ out_slots, int last){
  __shared__ float part[256][33];
  __shared__ float hL[256];
  __shared__ float lnh[256];
  __shared__ float hid[256];
  __shared__ float red[8];
  const int r = blockIdx.x, tid = threadIdx.x;
  const int lane = tid & 63, wv = tid >> 6;
  const float* gg = gigh + (size_t)r*6*256;
  float i_r = gg[tid],     i_z = gg[256+tid],  i_n = gg[512+tid];
  float h_r = gg[768+tid], h_z = gg[1024+tid], h_n = gg[1280+tid];
  float hp = slots[r*256 + tid];
  float rg = 1.f/(1.f + expf(-(i_r + h_r)));
  float zg = 1.f/(1.f + expf(-(i_z + h_z)));
  float ng = tanhf(i_n + rg*h_n);
  float h = (1.f - zg)*ng + zg*hp;
  hL[tid] = h;
  float v1 = h, v2 = h*h;
  #pragma unroll
  for (int o = 32; o; o >>= 1){ v1 += __shfl_xor(v1,o,64); v2 += __shfl_xor(v2,o,64); }
  if (lane == 0){ red[wv] = v1; red[4+wv] = v2; }
  __syncthreads();
  {
    float mu = (red[0]+red[1]+red[2]+red[3]) * (1.f/256.f);
    float var = (red[4]+red[5]+red[6]+red[7]) * (1.f/256.f) - mu*mu;
    float inv = rsqrtf(var + LN_EPS);
    lnh[tid] = (h - mu)*inv*g_ff[tid] + be_ff[tid];
  }
  __syncthreads();
  const int c8 = tid & 31, dp = tid >> 5;
  {
    float xs8[8];
    #pragma unroll
    for (int j = 0; j < 8; ++j) xs8[j] = lnh[c8*8 + j];
    const float* Wb = W1 + c8*8;
    #pragma unroll 4
    for (int di = 0; di < 32; ++di){
      int d = dp*32 + di;
      part[d][c8] = dot8f(Wb + (size_t)d*256, xs8);
    }
  }
  __syncthreads();
  {
    float acc = 0.f;
    #pragma unroll
    for (int p = 0; p < 32; ++p) acc += part[tid][p];
    hid[tid] = fmaxf(acc + b1[tid], 0.f);
  }
  __syncthreads();
  {
    float xs8[8];
    #pragma unroll
    for (int j = 0; j < 8; ++j) xs8[j] = hid[c8*8 + j];
    const float* Wb = W2 + c8*8;
    #pragma unroll 4
    for (int di = 0; di < 32; ++di){
      int d = dp*32 + di;
      part[d][c8] = dot8f(Wb + (size_t)d*256, xs8);
    }
  }
  __syncthreads();
  {
    float acc = 0.f;
    #pragma unroll
    for (int p = 0; p < 32; ++p) acc += part[tid][p];
    float out = hL[tid] + acc + b2[tid];
    slots[r*256 + tid] = out;
    if (last) out_slots[r*256 + tid] = out;
  }
}

extern "C" void kernel_launch(void* const* d_in, const int* in_sizes, int n_in,
                              void* d_out, int out_size, void* d_ws, size_t ws_size,
                              hipStream_t stream){
  const float* emb   = (const float*)d_in[0];
  const float* noise = (const float*)d_in[1];
  const float* smu   = (const float*)d_in[2];
  const float* slsig = (const float*)d_in[3];
  const float* Wk    = (const float*)d_in[4];
  const float* Wq    = (const float*)d_in[5];
  const float* Wv    = (const float*)d_in[6];
  const float* W_ih  = (const float*)d_in[7];
  const float* W_hh  = (const float*)d_in[8];
  const float* b_ih  = (const float*)d_in[9];
  const float* b_hh  = (const float*)d_in[10];
  const float* W1    = (const float*)d_in[11];
  const float* b1    = (const float*)d_in[12];
  const float* W2    = (const float*)d_in[13];
  const float* b2    = (const float*)d_in[14];
  const float* g_in  = (const float*)d_in[15];
  const float* be_in = (const float*)d_in[16];
  const float* g_s   = (const float*)d_in[17];
  const float* be_s  = (const float*)d_in[18];
  const float* g_ff  = (const float*)d_in[19];
  const float* be_ff = (const float*)d_in[20];

  float* ws    = (float*)d_ws;
  float* slots = ws;                 // 32768
  float* qg    = ws + 32768;         // 32768
  float* gqbq  = ws + 65536;         // 256
  float* upd   = ws + 65792;         // 32768
  float* gigh  = ws + 98560;         // 196608
  float* uacc  = ws + 295168;        // 32768
  float* Zacc  = ws + 327936;        // 128   (total ~1.3 MB)

  float* out_slots = (float*)d_out;
  float* out_attn  = out_slots + 32768;
  const int has_attn = (out_size >= 32768 + 16*8*4096);

  k_init_slots<<<dim3(128), dim3(256), 0, stream>>>(noise, smu, slsig, slots);
  for (int it = 0; it < 3; ++it){
    int last = (it == 2);
    k_qg<<<dim3(128), dim3(256), 0, stream>>>(slots, Wq, Wk, g_s, be_s, g_in, be_in, qg, gqbq, uacc, Zacc);
    k_main<<<dim3(2048), dim3(256), 0, stream>>>(emb, qg, gqbq, g_in, be_in, uacc, Zacc, out_attn, last && has_attn);
    k_updates<<<dim3(128), dim3(256), 0, stream>>>(uacc, Zacc, Wv, upd);
    k_gruGemv<<<dim3(6,128), dim3(256), 0, stream>>>(upd, slots, W_ih, W_hh, b_ih, b_hh, gigh);
    k_mlp<<<dim3(128), dim3(256), 0, stream>>>(gigh, slots, W1, b1, W2, b2, g_ff, be_ff, out_slots, last);
  }
}

// Round 5
// 383.226 us; speedup vs baseline: 1.0465x; 1.0465x over previous
//
#include <hip/hip_runtime.h>

#define DEVI __device__ __forceinline__

constexpr float SCALE = 0.0625f;   // 256^-0.5
constexpr float LN_EPS = 1e-5f;

DEVI float dot8f(const float* __restrict__ w, const float* __restrict__ x){
  float4 a = *(const float4*)w;
  float4 b = *(const float4*)(w + 4);
  return a.x*x[0]+a.y*x[1]+a.z*x[2]+a.w*x[3]+b.x*x[4]+b.y*x[5]+b.z*x[6]+b.w*x[7];
}

// out[tid] = dot(W[tid][:], xv[:]) for a 256x256 row-major W. All 256 threads
// must call; xv must be synced by caller; ends with a trailing __syncthreads.
DEVI float gemv256(const float* __restrict__ W, const float* __restrict__ xv,
                   float (*part)[33], int tid){
  const int c8 = tid & 31, dp = tid >> 5;
  float xs8[8];
  #pragma unroll
  for (int j = 0; j < 8; ++j) xs8[j] = xv[c8*8 + j];
  #pragma unroll 4
  for (int di = 0; di < 32; ++di){
    int d = dp*32 + di;
    part[d][c8] = dot8f(W + (size_t)d*256 + c8*8, xs8);
  }
  __syncthreads();
  float acc = 0.f;
  #pragma unroll
  for (int p = 0; p < 32; ++p) acc += part[tid][p];
  __syncthreads();
  return acc;
}

// LayerNorm over the 256 values held one-per-thread. red is 8 floats of LDS.
DEVI float block_ln(float x, const float* __restrict__ g, const float* __restrict__ be,
                    float* red, int tid, int lane, int wv){
  float v1 = x, v2 = x*x;
  #pragma unroll
  for (int o = 32; o; o >>= 1){ v1 += __shfl_xor(v1,o,64); v2 += __shfl_xor(v2,o,64); }
  if (lane == 0){ red[wv] = v1; red[4+wv] = v2; }
  __syncthreads();
  float mu = (red[0]+red[1]+red[2]+red[3]) * (1.f/256.f);
  float var = (red[4]+red[5]+red[6]+red[7]) * (1.f/256.f) - mu*mu;
  float inv = rsqrtf(var + LN_EPS);
  float r = (x - mu)*inv*g[tid] + be[tid];
  __syncthreads();
  return r;
}

// q-generation tail: from new slot value snew (one per thread) produce
// qg[r] = SCALE*g_in*((LN_s(snew)@Wq^T)@Wk[s]) and the Gq/Bq scalars.
DEVI void q_gen(float snew, int r, int s, int tid, int lane, int wv,
                const float* __restrict__ Wq, const float* __restrict__ Wk,
                const float* __restrict__ g_s, const float* __restrict__ be_s,
                const float* __restrict__ g_in, const float* __restrict__ be_in,
                float* __restrict__ qg, float* __restrict__ gqbq,
                float* xv, float (*part)[33], float (*partK)[256], float* red){
  float sn = block_ln(snew, g_s, be_s, red, tid, lane, wv);
  xv[tid] = sn; __syncthreads();
  float q = gemv256(Wq, xv, part, tid);
  xv[tid] = q; __syncthreads();
  // qk[d] = sum_e q[e] * Wk[s][e][d]  (outer-product over e, coalesced in d)
  const int c8 = tid & 31, ep = tid >> 5;
  float acc8[8];
  #pragma unroll
  for (int j = 0; j < 8; ++j) acc8[j] = 0.f;
  const float* Wb = Wk + ((size_t)s*256)*256 + c8*8;
  #pragma unroll 4
  for (int ei = 0; ei < 32; ++ei){
    int e = ep*32 + ei;
    const float* wp = Wb + (size_t)e*256;
    float4 wa = *(const float4*)wp;
    float4 wb = *(const float4*)(wp + 4);
    float qe = xv[e];
    acc8[0] += qe*wa.x; acc8[1] += qe*wa.y; acc8[2] += qe*wa.z; acc8[3] += qe*wa.w;
    acc8[4] += qe*wb.x; acc8[5] += qe*wb.y; acc8[6] += qe*wb.z; acc8[7] += qe*wb.w;
  }
  float* pk = &partK[ep][c8*8];
  #pragma unroll
  for (int j = 0; j < 8; ++j) pk[j] = acc8[j];
  __syncthreads();
  float qk = 0.f;
  #pragma unroll
  for (int p = 0; p < 8; ++p) qk += partK[p][tid];
  float qgv = qk * g_in[tid] * SCALE;
  float bqv = qk * be_in[tid] * SCALE;
  qg[r*256 + tid] = qgv;
  float vq = qgv, vb = bqv;
  #pragma unroll
  for (int o = 32; o; o >>= 1){ vq += __shfl_xor(vq,o,64); vb += __shfl_xor(vb,o,64); }
  if (lane == 0){ red[wv] = vq; red[4+wv] = vb; }
  __syncthreads();
  if (tid == 0) gqbq[r*2+0] = red[0]+red[1]+red[2]+red[3];
  if (tid == 1) gqbq[r*2+1] = red[4]+red[5]+red[6]+red[7];
}

// ---------------- K0: slots init + zero accumulators + first q-gen ----------------
__global__ __launch_bounds__(256) void k_qg0(const float* __restrict__ noise,
    const float* __restrict__ smu, const float* __restrict__ slsig,
    const float* __restrict__ Wq, const float* __restrict__ Wk,
    const float* __restrict__ g_s, const float* __restrict__ be_s,
    const float* __restrict__ g_in, const float* __restrict__ be_in,
    float* __restrict__ slots, float* __restrict__ qg, float* __restrict__ gqbq,
    float* __restrict__ uacc, float* __restrict__ Zacc){
  __shared__ float part[256][33];
  __shared__ float partK[8][256];
  __shared__ float xv[256];
  __shared__ float red[8];
  const int r = blockIdx.x, tid = threadIdx.x;
  const int s = r & 7, lane = tid & 63, wv = tid >> 6;
  float x = smu[s*256 + tid] + expf(slsig[s*256 + tid]) * noise[r*256 + tid];
  slots[r*256 + tid] = x;
  uacc[r*256 + tid] = 0.f;
  if (tid == 0) Zacc[r] = 0.f;
  q_gen(x, r, s, tid, lane, wv, Wq, Wk, g_s, be_s, g_in, be_in, qg, gqbq,
        xv, part, partK, red);
}

// ---------------- K1: fused LN + dots + softmax(slots) + weighted-emb accumulation --------
// one block = 32-token tile. No X staging in LDS: phase 1 streams emb (float4,
// fused LN-stats + dots); phase 2 re-reads the tile column-wise (L1/L2-hot).
__global__ __launch_bounds__(256) void k_main(const float* __restrict__ emb,
    const float* __restrict__ qg, const float* __restrict__ gqbq,
    const float* __restrict__ g_in, const float* __restrict__ be_in,
    float* __restrict__ uacc, float* __restrict__ Zacc,
    float* __restrict__ out_attn, int write_attn){
  __shared__ float qgL[2048];       // bank-swizzled: f4 (s,qq,j) at s*64+qq*8+((j+qq)&7)
  __shared__ float aL[256], avL[256];
  __shared__ float Wred[2][8][4];
  __shared__ float Zs[8], A2s[8], GqL[8], BqL[8];

  const int tid = threadIdx.x, lane = tid & 63, wv = tid >> 6;
  const int blk = blockIdx.x, b = blk >> 7, tile = blk & 127;
  const int n0 = tile * 32;

  { // stage queries with a per-qq rotation so the 8 qq-chunks hit distinct banks
    const float4* src = (const float4*)(qg + (size_t)b * 2048);
    float4* dst = (float4*)qgL;
    #pragma unroll
    for (int k = 0; k < 2; ++k){
      int w = tid + k*256;                 // 0..511
      int s = w >> 6, f = w & 63, qq = f >> 3, j = f & 7;
      dst[s*64 + qq*8 + ((j + qq) & 7)] = src[w];
    }
  }
  if (tid < 8){
    GqL[tid] = gqbq[(b*8 + tid)*2 + 0];
    BqL[tid] = gqbq[(b*8 + tid)*2 + 1];
  }
  __syncthreads();

  const int t = tid >> 3;   // token 0..31 (8 lanes per token)
  const int qq = tid & 7;   // 32-col chunk
  { // fused LN stats + dots, straight from global (coalesced float4)
    const float4* xrow = (const float4*)(emb + ((size_t)(b*4096 + n0 + t))*256 + qq*32);
    float4 xv4[8];
    #pragma unroll
    for (int j = 0; j < 8; ++j) xv4[j] = xrow[j];
    float s1 = 0.f, s2 = 0.f, acc[8];
    #pragma unroll
    for (int s = 0; s < 8; ++s) acc[s] = 0.f;
    #pragma unroll
    for (int j = 0; j < 8; ++j){
      float4 u = xv4[j];
      s1 += (u.x+u.y)+(u.z+u.w);
      s2 += u.x*u.x+u.y*u.y+u.z*u.z+u.w*u.w;
      const float* qb = qgL + qq*32 + ((j + qq) & 7)*4;
      #pragma unroll
      for (int s = 0; s < 8; ++s){
        float4 q0 = *(const float4*)(qb + s*256);
        acc[s] += u.x*q0.x + u.y*q0.y + u.z*q0.z + u.w*q0.w;
      }
    }
    #pragma unroll
    for (int o = 1; o <= 4; o <<= 1){
      s1 += __shfl_xor(s1,o,64); s2 += __shfl_xor(s2,o,64);
      #pragma unroll
      for (int s = 0; s < 8; ++s) acc[s] += __shfl_xor(acc[s],o,64);
    }
    float mu = s1 * (1.f/256.f);
    float var = s2 * (1.f/256.f) - mu*mu;
    float inv = rsqrtf(var + LN_EPS);
    float dv[8], mx = -1e30f;
    #pragma unroll
    for (int s = 0; s < 8; ++s){
      dv[s] = inv * (acc[s] - mu * GqL[s]) + BqL[s];
      mx = fmaxf(mx, dv[s]);
    }
    float den = 0.f;
    #pragma unroll
    for (int s = 0; s < 8; ++s){ dv[s] = expf(dv[s] - mx); den += dv[s]; }
    float rden = 1.f / den;
    #pragma unroll
    for (int s = 0; s < 8; ++s){
      float at = dv[s] * rden;       // attn (softmax over slots)
      float av = at * inv;           // attn * inv (LN folded)
      if (qq == 0){ avL[s*32 + t] = at; aL[s*32 + t] = av; }
      float z1 = at, z2 = av * mu;
      #pragma unroll
      for (int o = 32; o; o >>= 1){ z1 += __shfl_xor(z1, o, 64); z2 += __shfl_xor(z2, o, 64); }
      if (lane == 0){ Wred[0][s][wv] = z1 * 0.125f; Wred[1][s][wv] = z2 * 0.125f; }
    }
  }
  __syncthreads();
  if (tid < 8){
    Zs[tid]  = Wred[0][tid][0]+Wred[0][tid][1]+Wred[0][tid][2]+Wred[0][tid][3];
    A2s[tid] = Wred[1][tid][0]+Wred[1][tid][1]+Wred[1][tid][2]+Wred[1][tid][3];
  }
  if (write_attn){
    int s = tid >> 5, tk = tid & 31;
    out_attn[((size_t)(b*8 + s))*4096 + n0 + tk] = avL[s*32 + tk];
  }
  __syncthreads();
  { // phase 2: column re-read (L1/L2-hot), token-weighted accumulation + atomics
    const int c = tid;
    const float* xcol = emb + ((size_t)(b*4096 + n0))*256 + c;
    float S1[8];
    #pragma unroll
    for (int s = 0; s < 8; ++s) S1[s] = 0.f;
    #pragma unroll 2
    for (int t4 = 0; t4 < 8; ++t4){
      float x0 = xcol[(t4*4+0)*256];
      float x1 = xcol[(t4*4+1)*256];
      float x2 = xcol[(t4*4+2)*256];
      float x3 = xcol[(t4*4+3)*256];
      #pragma unroll
      for (int s = 0; s < 8; ++s){
        float4 a4 = *(const float4*)(&aL[s*32 + t4*4]);   // broadcast
        S1[s] += x0*a4.x + x1*a4.y + x2*a4.z + x3*a4.w;
      }
    }
    float gc = g_in[c], bc = be_in[c];
    float* dst = uacc + ((size_t)b*8)*256 + c;
    #pragma unroll
    for (int s = 0; s < 8; ++s){
      atomicAdd(&dst[s*256], gc * (S1[s] - A2s[s]) + bc * Zs[s]);
    }
    if (tid < 8) atomicAdd(&Zacc[b*8 + tid], Zs[tid]);
  }
}

// ---------------- K2: fused updates + GRU + MLP + residual + next-iter q-gen ----------------
__global__ __launch_bounds__(256) void k_fused(
    float* __restrict__ slots, float* __restrict__ uacc, float* __restrict__ Zacc,
    const float* __restrict__ Wv,
    const float* __restrict__ W_ih, const float* __restrict__ W_hh,
    const float* __restrict__ b_ih, const float* __restrict__ b_hh,
    const float* __restrict__ W1, const float* __restrict__ b1,
    const float* __restrict__ W2, const float* __restrict__ b2,
    const float* __restrict__ g_ff, const float* __restrict__ be_ff,
    const float* __restrict__ Wq, const float* __restrict__ Wk,
    const float* __restrict__ g_s, const float* __restrict__ be_s,
    const float* __restrict__ g_in, const float* __restrict__ be_in,
    float* __restrict__ qg, float* __restrict__ gqbq,
    float* __restrict__ out_slots, int last){
  __shared__ float part[256][33];
  __shared__ float partK[8][256];
  __shared__ float xv[256];
  __shared__ float red[8];
  __shared__ float zsh;
  const int r = blockIdx.x, tid = threadIdx.x;
  const int s = r & 7, lane = tid & 63, wv = tid >> 6;

  float u = uacc[r*256 + tid];
  uacc[r*256 + tid] = 0.f;                 // re-zero for next k_main
  if (tid == 0){ zsh = Zacc[r]; Zacc[r] = 0.f; }
  xv[tid] = u;
  __syncthreads();
  const float rz = 1.f / zsh;
  float upd = gemv256(Wv + (size_t)s*65536, xv, part, tid) * rz;

  xv[tid] = upd; __syncthreads();
  float i_r = gemv256(W_ih,           xv, part, tid) + b_ih[tid];
  float i_z = gemv256(W_ih +  65536,  xv, part, tid) + b_ih[256 + tid];
  float i_n = gemv256(W_ih + 131072,  xv, part, tid) + b_ih[512 + tid];

  float hp = slots[r*256 + tid];
  xv[tid] = hp; __syncthreads();
  float h_r = gemv256(W_hh,           xv, part, tid) + b_hh[tid];
  float h_z = gemv256(W_hh +  65536,  xv, part, tid) + b_hh[256 + tid];
  float h_n = gemv256(W_hh + 131072,  xv, part, tid) + b_hh[512 + tid];

  float rg = 1.f/(1.f + expf(-(i_r + h_r)));
  float zg = 1.f/(1.f + expf(-(i_z + h_z)));
  float ng = tanhf(i_n + rg*h_n);
  float h  = (1.f - zg)*ng + zg*hp;

  float lnh = block_ln(h, g_ff, be_ff, red, tid, lane, wv);
  xv[tid] = lnh; __syncthreads();
  float hid = fmaxf(gemv256(W1, xv, part, tid) + b1[tid], 0.f);
  xv[tid] = hid; __syncthreads();
  float out = h + gemv256(W2, xv, part, tid) + b2[tid];
  slots[r*256 + tid] = out;
  if (last){
    out_slots[r*256 + tid] = out;
    return;
  }
  q_gen(out, r, s, tid, lane, wv, Wq, Wk, g_s, be_s, g_in, be_in, qg, gqbq,
        xv, part, partK, red);
}

extern "C" void kernel_launch(void* const* d_in, const int* in_sizes, int n_in,
                              void* d_out, int out_size, void* d_ws, size_t ws_size,
                              hipStream_t stream){
  const float* emb   = (const float*)d_in[0];
  const float* noise = (const float*)d_in[1];
  const float* smu   = (const float*)d_in[2];
  const float* slsig = (const float*)d_in[3];
  const float* Wk    = (const float*)d_in[4];
  const float* Wq    = (const float*)d_in[5];
  const float* Wv    = (const float*)d_in[6];
  const float* W_ih  = (const float*)d_in[7];
  const float* W_hh  = (const float*)d_in[8];
  const float* b_ih  = (const float*)d_in[9];
  const float* b_hh  = (const float*)d_in[10];
  const float* W1    = (const float*)d_in[11];
  const float* b1    = (const float*)d_in[12];
  const float* W2    = (const float*)d_in[13];
  const float* b2    = (const float*)d_in[14];
  const float* g_in  = (const float*)d_in[15];
  const float* be_in = (const float*)d_in[16];
  const float* g_s   = (const float*)d_in[17];
  const float* be_s  = (const float*)d_in[18];
  const float* g_ff  = (const float*)d_in[19];
  const float* be_ff = (const float*)d_in[20];

  float* ws    = (float*)d_ws;
  float* slots = ws;                 // 32768
  float* qg    = ws + 32768;         // 32768
  float* gqbq  = ws + 65536;         // 256
  float* uacc  = ws + 65792;         // 32768
  float* Zacc  = ws + 98560;         // 128   (total ~395 KB)

  float* out_slots = (float*)d_out;
  float* out_attn  = out_slots + 32768;
  const int has_attn = (out_size >= 32768 + 16*8*4096);

  k_qg0<<<dim3(128), dim3(256), 0, stream>>>(noise, smu, slsig, Wq, Wk,
      g_s, be_s, g_in, be_in, slots, qg, gqbq, uacc, Zacc);
  for (int it = 0; it < 3; ++it){
    int last = (it == 2);
    k_main<<<dim3(2048), dim3(256), 0, stream>>>(emb, qg, gqbq, g_in, be_in,
        uacc, Zacc, out_attn, last && has_attn);
    k_fused<<<dim3(128), dim3(256), 0, stream>>>(slots, uacc, Zacc, Wv,
        W_ih, W_hh, b_ih, b_hh, W1, b1, W2, b2, g_ff, be_ff,
        Wq, Wk, g_s, be_s, g_in, be_in, qg, gqbq, out_slots, last);
  }
}

// Round 6
// 362.333 us; speedup vs baseline: 1.1069x; 1.0577x over previous
//
#include <hip/hip_runtime.h>

#define DEVI __device__ __forceinline__

constexpr float SCALE = 0.0625f;   // 256^-0.5
constexpr float LN_EPS = 1e-5f;

DEVI float dot8f(const float* __restrict__ w, const float* __restrict__ x){
  float4 a = *(const float4*)w;
  float4 b = *(const float4*)(w + 4);
  return a.x*x[0]+a.y*x[1]+a.z*x[2]+a.w*x[3]+b.x*x[4]+b.y*x[5]+b.z*x[6]+b.w*x[7];
}

// 1024-thread 256x256 GEMV: out[d] = dot(W[d][:], xv[:]). Thread (c8=tid&31,
// dp=tid>>5) computes 8 outputs' partial over k-chunk c8. Valid for tid<256.
// Two internal syncs; xv/part reusable after return.
DEVI float gemv256_w(const float* __restrict__ W, const float* __restrict__ xv,
                     float (*part)[33], int tid){
  const int c8 = tid & 31, dp = tid >> 5;   // dp 0..31
  float xs8[8];
  #pragma unroll
  for (int j = 0; j < 8; ++j) xs8[j] = xv[c8*8 + j];
  #pragma unroll
  for (int di = 0; di < 8; ++di){
    int d = dp*8 + di;
    part[d][c8] = dot8f(W + (size_t)d*256 + c8*8, xs8);
  }
  __syncthreads();
  float acc = 0.f;
  if (tid < 256){
    #pragma unroll
    for (int p = 0; p < 32; ++p) acc += part[tid][p];
  }
  __syncthreads();
  return acc;
}

// LayerNorm over 256 values held by tid<256 (one each). All 1024 threads call.
DEVI float block_ln2(float x, const float* __restrict__ g, const float* __restrict__ be,
                     float* red, int tid){
  const int lane = tid & 63, wv = tid >> 6;
  float v1 = x, v2 = x*x;
  #pragma unroll
  for (int o = 32; o; o >>= 1){ v1 += __shfl_xor(v1,o,64); v2 += __shfl_xor(v2,o,64); }
  if (tid < 256 && lane == 0){ red[wv] = v1; red[4+wv] = v2; }
  __syncthreads();
  float mu = (red[0]+red[1]+red[2]+red[3]) * (1.f/256.f);
  float var = (red[4]+red[5]+red[6]+red[7]) * (1.f/256.f) - mu*mu;
  float inv = rsqrtf(var + LN_EPS);
  float r = 0.f;
  if (tid < 256) r = (x - mu)*inv*g[tid] + be[tid];
  __syncthreads();
  return r;
}

// q-gen tail (1024 threads): qg[r] = SCALE*g_in*((LN_s(snew)@Wq^T)@Wk[s]), Gq/Bq.
DEVI void q_gen(float snew, int r, int s, int tid,
                const float* __restrict__ Wq, const float* __restrict__ Wk,
                const float* __restrict__ g_s, const float* __restrict__ be_s,
                const float* __restrict__ g_in, const float* __restrict__ be_in,
                float* __restrict__ qg, float* __restrict__ gqbq,
                float* xv, float (*part)[33], float (*partK)[256], float* red){
  float sn = block_ln2(snew, g_s, be_s, red, tid);
  if (tid < 256) xv[tid] = sn;
  __syncthreads();
  float q = gemv256_w(Wq, xv, part, tid);
  if (tid < 256) xv[tid] = q;
  __syncthreads();
  // qk[d] = sum_e q[e] * Wk[s][e][d]  (outer-product over e, coalesced in d)
  const int c8 = tid & 31, ep = tid >> 5;   // ep 0..31, 8 e's each
  float acc8[8];
  #pragma unroll
  for (int j = 0; j < 8; ++j) acc8[j] = 0.f;
  const float* Wb = Wk + ((size_t)s*256)*256 + c8*8;
  #pragma unroll
  for (int ei = 0; ei < 8; ++ei){
    int e = ep*8 + ei;
    const float* wp = Wb + (size_t)e*256;
    float4 wa = *(const float4*)wp;
    float4 wb = *(const float4*)(wp + 4);
    float qe = xv[e];
    acc8[0] += qe*wa.x; acc8[1] += qe*wa.y; acc8[2] += qe*wa.z; acc8[3] += qe*wa.w;
    acc8[4] += qe*wb.x; acc8[5] += qe*wb.y; acc8[6] += qe*wb.z; acc8[7] += qe*wb.w;
  }
  float* pk = &partK[ep][c8*8];
  #pragma unroll
  for (int j = 0; j < 8; ++j) pk[j] = acc8[j];
  __syncthreads();
  float vq = 0.f, vb = 0.f;
  if (tid < 256){
    float qk = 0.f;
    #pragma unroll
    for (int p = 0; p < 32; ++p) qk += partK[p][tid];
    float qgv = qk * g_in[tid] * SCALE;
    float bqv = qk * be_in[tid] * SCALE;
    qg[r*256 + tid] = qgv;
    vq = qgv; vb = bqv;
  }
  #pragma unroll
  for (int o = 32; o; o >>= 1){ vq += __shfl_xor(vq,o,64); vb += __shfl_xor(vb,o,64); }
  if (tid < 256 && (tid & 63) == 0){ red[tid>>6] = vq; red[4+(tid>>6)] = vb; }
  __syncthreads();
  if (tid == 0) gqbq[r*2+0] = red[0]+red[1]+red[2]+red[3];
  if (tid == 1) gqbq[r*2+1] = red[4]+red[5]+red[6]+red[7];
}

// ---------------- K0: slots init + zero accumulators + first q-gen ----------------
__global__ __launch_bounds__(1024) void k_qg0(const float* __restrict__ noise,
    const float* __restrict__ smu, const float* __restrict__ slsig,
    const float* __restrict__ Wq, const float* __restrict__ Wk,
    const float* __restrict__ g_s, const float* __restrict__ be_s,
    const float* __restrict__ g_in, const float* __restrict__ be_in,
    float* __restrict__ slots, float* __restrict__ qg, float* __restrict__ gqbq,
    float* __restrict__ uacc, float* __restrict__ Zacc){
  __shared__ float part[256][33];
  __shared__ float partK[32][256];
  __shared__ float xv[256];
  __shared__ float red[8];
  const int r = blockIdx.x, tid = threadIdx.x;
  const int s = r & 7;
  float x = 0.f;
  if (tid < 256){
    x = smu[s*256 + tid] + expf(slsig[s*256 + tid]) * noise[r*256 + tid];
    slots[r*256 + tid] = x;
    uacc[r*256 + tid] = 0.f;
  }
  if (tid == 0) Zacc[r] = 0.f;
  q_gen(x, r, s, tid, Wq, Wk, g_s, be_s, g_in, be_in, qg, gqbq, xv, part, partK, red);
}

// ---------------- K1: fused LN + dots + softmax(slots) + weighted-emb accumulation --------
// one block = 64-token tile. Phase 1 streams emb (float4, fused LN+dots, 2 passes);
// phase 2 re-reads the tile coalesced (f4 column-parallel) + 4-wave LDS reduce.
__global__ __launch_bounds__(256) void k_main(const float* __restrict__ emb,
    const float* __restrict__ qg, const float* __restrict__ gqbq,
    const float* __restrict__ g_in, const float* __restrict__ be_in,
    float* __restrict__ uacc, float* __restrict__ Zacc,
    float* __restrict__ out_attn, int write_attn){
  __shared__ float qgL[2048];       // bank-swizzled: f4 (s,qq,j) at s*64+qq*8+((j+qq)&7)
  __shared__ float aL[512], avL[512];          // [s][t] t<64
  __shared__ float4 Sp4[4*8*64];               // [r4][s][cq] partials, 32 KB
  __shared__ float red2[2][8][4];
  __shared__ float Zs[8], A2s[8], GqL[8], BqL[8];

  const int tid = threadIdx.x, lane = tid & 63, wv = tid >> 6;
  const int blk = blockIdx.x, b = blk >> 6, tile = blk & 63;
  const int n0 = tile * 64;

  { // stage queries with per-qq rotation so the 8 qq-chunks hit distinct banks
    const float4* src = (const float4*)(qg + (size_t)b * 2048);
    float4* dst = (float4*)qgL;
    #pragma unroll
    for (int k = 0; k < 2; ++k){
      int w = tid + k*256;                 // 0..511
      int s = w >> 6, f = w & 63, qq = f >> 3, j = f & 7;
      dst[s*64 + qq*8 + ((j + qq) & 7)] = src[w];
    }
  }
  if (tid < 8){
    GqL[tid] = gqbq[(b*8 + tid)*2 + 0];
    BqL[tid] = gqbq[(b*8 + tid)*2 + 1];
  }
  __syncthreads();

  const int qq = tid & 7;   // 32-col chunk
  float zsum[8], z2sum[8];
  #pragma unroll
  for (int s = 0; s < 8; ++s){ zsum[s] = 0.f; z2sum[s] = 0.f; }

  #pragma unroll
  for (int pass = 0; pass < 2; ++pass){
    const int t = pass*32 + (tid >> 3);   // token 0..63
    const float4* xrow = (const float4*)(emb + ((size_t)(b*4096 + n0 + t))*256 + qq*32);
    float4 xv4[8];
    #pragma unroll
    for (int j = 0; j < 8; ++j) xv4[j] = xrow[j];
    float s1 = 0.f, s2 = 0.f, acc[8];
    #pragma unroll
    for (int s = 0; s < 8; ++s) acc[s] = 0.f;
    #pragma unroll
    for (int j = 0; j < 8; ++j){
      float4 u = xv4[j];
      s1 += (u.x+u.y)+(u.z+u.w);
      s2 += u.x*u.x+u.y*u.y+u.z*u.z+u.w*u.w;
      const float* qb = qgL + qq*32 + ((j + qq) & 7)*4;
      #pragma unroll
      for (int s = 0; s < 8; ++s){
        float4 q0 = *(const float4*)(qb + s*256);
        acc[s] += u.x*q0.x + u.y*q0.y + u.z*q0.z + u.w*q0.w;
      }
    }
    #pragma unroll
    for (int o = 1; o <= 4; o <<= 1){
      s1 += __shfl_xor(s1,o,64); s2 += __shfl_xor(s2,o,64);
      #pragma unroll
      for (int s = 0; s < 8; ++s) acc[s] += __shfl_xor(acc[s],o,64);
    }
    float mu = s1 * (1.f/256.f);
    float var = s2 * (1.f/256.f) - mu*mu;
    float inv = rsqrtf(var + LN_EPS);
    float dv[8], mx = -1e30f;
    #pragma unroll
    for (int s = 0; s < 8; ++s){
      dv[s] = inv * (acc[s] - mu * GqL[s]) + BqL[s];
      mx = fmaxf(mx, dv[s]);
    }
    float den = 0.f;
    #pragma unroll
    for (int s = 0; s < 8; ++s){ dv[s] = expf(dv[s] - mx); den += dv[s]; }
    float rden = 1.f / den;
    #pragma unroll
    for (int s = 0; s < 8; ++s){
      float at = dv[s] * rden;       // attn (softmax over slots)
      float av = at * inv;           // attn * inv (LN folded)
      if (qq == 0){ avL[s*64 + t] = at; aL[s*64 + t] = av; }
      float z1 = at, z2 = av * mu;
      #pragma unroll
      for (int o = 32; o; o >>= 1){ z1 += __shfl_xor(z1, o, 64); z2 += __shfl_xor(z2, o, 64); }
      zsum[s] += z1 * 0.125f;        // 8 lanes per token
      z2sum[s] += z2 * 0.125f;
    }
  }
  if (lane == 0){
    #pragma unroll
    for (int s = 0; s < 8; ++s){ red2[0][s][wv] = zsum[s]; red2[1][s][wv] = z2sum[s]; }
  }
  __syncthreads();
  if (tid < 8){
    Zs[tid]  = red2[0][tid][0]+red2[0][tid][1]+red2[0][tid][2]+red2[0][tid][3];
    A2s[tid] = red2[1][tid][0]+red2[1][tid][1]+red2[1][tid][2]+red2[1][tid][3];
  }
  if (write_attn){
    int s = tid >> 5, tk = tid & 31;
    #pragma unroll
    for (int p = 0; p < 2; ++p)
      out_attn[((size_t)(b*8 + s))*4096 + n0 + p*32 + tk] = avL[s*64 + p*32 + tk];
  }
  __syncthreads();
  { // phase 2: coalesced f4 token-weighted accumulation
    const int r4 = tid >> 6, cq = tid & 63;
    float4 S1[8];
    #pragma unroll
    for (int s = 0; s < 8; ++s) S1[s] = make_float4(0.f,0.f,0.f,0.f);
    const float4* xbase = (const float4*)(emb + ((size_t)(b*4096 + n0))*256) + cq;
    #pragma unroll 4
    for (int i = 0; i < 16; ++i){
      int t = r4 + i*4;
      float4 x4 = xbase[t*64];
      #pragma unroll
      for (int s = 0; s < 8; ++s){
        float a = aL[s*64 + t];   // wave-uniform broadcast
        S1[s].x += a*x4.x; S1[s].y += a*x4.y; S1[s].z += a*x4.z; S1[s].w += a*x4.w;
      }
    }
    #pragma unroll
    for (int s = 0; s < 8; ++s) Sp4[(r4*8 + s)*64 + cq] = S1[s];
  }
  __syncthreads();
  { // final: sum 4 wave-partials per (s,c), atomically accumulate (s staggered)
    const int c = tid;
    const float* Sp = (const float*)Sp4;
    float gc = g_in[c], bc = be_in[c];
    float* dst = uacc + ((size_t)b*8)*256 + c;
    #pragma unroll
    for (int si = 0; si < 8; ++si){
      int s = (si + blk) & 7;
      float v = Sp[(0*8+s)*256 + c] + Sp[(1*8+s)*256 + c]
              + Sp[(2*8+s)*256 + c] + Sp[(3*8+s)*256 + c];
      atomicAdd(&dst[s*256], gc * (v - A2s[s]) + bc * Zs[s]);
    }
    if (tid < 8) atomicAdd(&Zacc[b*8 + tid], Zs[tid]);
  }
}

// ---------------- K2: fused updates + GRU + MLP + residual + next-iter q-gen ----------------
__global__ __launch_bounds__(1024) void k_fused(
    float* __restrict__ slots, float* __restrict__ uacc, float* __restrict__ Zacc,
    const float* __restrict__ Wv,
    const float* __restrict__ W_ih, const float* __restrict__ W_hh,
    const float* __restrict__ b_ih, const float* __restrict__ b_hh,
    const float* __restrict__ W1, const float* __restrict__ b1,
    const float* __restrict__ W2, const float* __restrict__ b2,
    const float* __restrict__ g_ff, const float* __restrict__ be_ff,
    const float* __restrict__ Wq, const float* __restrict__ Wk,
    const float* __restrict__ g_s, const float* __restrict__ be_s,
    const float* __restrict__ g_in, const float* __restrict__ be_in,
    float* __restrict__ qg, float* __restrict__ gqbq,
    float* __restrict__ out_slots, int last){
  __shared__ float part[256][33];
  __shared__ float partK[32][256];
  __shared__ float xv[256];
  __shared__ float red[8];
  __shared__ float zsh;
  const int r = blockIdx.x, tid = threadIdx.x;
  const int s = r & 7;

  float u = 0.f, hp = 0.f;
  if (tid < 256){
    u = uacc[r*256 + tid];
    uacc[r*256 + tid] = 0.f;                 // re-zero for next k_main
    xv[tid] = u;
  }
  if (tid == 0){ zsh = Zacc[r]; Zacc[r] = 0.f; }
  __syncthreads();
  const float rz = 1.f / zsh;
  float upd = gemv256_w(Wv + (size_t)s*65536, xv, part, tid) * rz;

  if (tid < 256) xv[tid] = upd;
  __syncthreads();
  float i_r = gemv256_w(W_ih,          xv, part, tid);
  float i_z = gemv256_w(W_ih +  65536, xv, part, tid);
  float i_n = gemv256_w(W_ih + 131072, xv, part, tid);

  if (tid < 256){
    hp = slots[r*256 + tid];
    xv[tid] = hp;
  }
  __syncthreads();
  float h_r = gemv256_w(W_hh,          xv, part, tid);
  float h_z = gemv256_w(W_hh +  65536, xv, part, tid);
  float h_n = gemv256_w(W_hh + 131072, xv, part, tid);

  float h = 0.f;
  if (tid < 256){
    i_r += b_ih[tid];       h_r += b_hh[tid];
    i_z += b_ih[256 + tid]; h_z += b_hh[256 + tid];
    i_n += b_ih[512 + tid]; h_n += b_hh[512 + tid];
    float rg = 1.f/(1.f + expf(-(i_r + h_r)));
    float zg = 1.f/(1.f + expf(-(i_z + h_z)));
    float ng = tanhf(i_n + rg*h_n);
    h = (1.f - zg)*ng + zg*hp;
  }
  float lnh = block_ln2(h, g_ff, be_ff, red, tid);
  if (tid < 256) xv[tid] = lnh;
  __syncthreads();
  float hid = gemv256_w(W1, xv, part, tid);
  if (tid < 256) xv[tid] = fmaxf(hid + b1[tid], 0.f);
  __syncthreads();
  float o2 = gemv256_w(W2, xv, part, tid);
  float out = 0.f;
  if (tid < 256){
    out = h + o2 + b2[tid];
    slots[r*256 + tid] = out;
    if (last) out_slots[r*256 + tid] = out;
  }
  if (last) return;
  q_gen(out, r, s, tid, Wq, Wk, g_s, be_s, g_in, be_in, qg, gqbq, xv, part, partK, red);
}

extern "C" void kernel_launch(void* const* d_in, const int* in_sizes, int n_in,
                              void* d_out, int out_size, void* d_ws, size_t ws_size,
                              hipStream_t stream){
  const float* emb   = (const float*)d_in[0];
  const float* noise = (const float*)d_in[1];
  const float* smu   = (const float*)d_in[2];
  const float* slsig = (const float*)d_in[3];
  const float* Wk    = (const float*)d_in[4];
  const float* Wq    = (const float*)d_in[5];
  const float* Wv    = (const float*)d_in[6];
  const float* W_ih  = (const float*)d_in[7];
  const float* W_hh  = (const float*)d_in[8];
  const float* b_ih  = (const float*)d_in[9];
  const float* b_hh  = (const float*)d_in[10];
  const float* W1    = (const float*)d_in[11];
  const float* b1    = (const float*)d_in[12];
  const float* W2    = (const float*)d_in[13];
  const float* b2    = (const float*)d_in[14];
  const float* g_in  = (const float*)d_in[15];
  const float* be_in = (const float*)d_in[16];
  const float* g_s   = (const float*)d_in[17];
  const float* be_s  = (const float*)d_in[18];
  const float* g_ff  = (const float*)d_in[19];
  const float* be_ff = (const float*)d_in[20];

  float* ws    = (float*)d_ws;
  float* slots = ws;                 // 32768
  float* qg    = ws + 32768;         // 32768
  float* gqbq  = ws + 65536;         // 256
  float* uacc  = ws + 65792;         // 32768
  float* Zacc  = ws + 98560;         // 128   (total ~395 KB)

  float* out_slots = (float*)d_out;
  float* out_attn  = out_slots + 32768;
  const int has_attn = (out_size >= 32768 + 16*8*4096);

  k_qg0<<<dim3(128), dim3(1024), 0, stream>>>(noise, smu, slsig, Wq, Wk,
      g_s, be_s, g_in, be_in, slots, qg, gqbq, uacc, Zacc);
  for (int it = 0; it < 3; ++it){
    int last = (it == 2);
    k_main<<<dim3(1024), dim3(256), 0, stream>>>(emb, qg, gqbq, g_in, be_in,
        uacc, Zacc, out_attn, last && has_attn);
    k_fused<<<dim3(128), dim3(1024), 0, stream>>>(slots, uacc, Zacc, Wv,
        W_ih, W_hh, b_ih, b_hh, W1, b1, W2, b2, g_ff, be_ff,
        Wq, Wk, g_s, be_s, g_in, be_in, qg, gqbq, out_slots, last);
  }
}